// Round 1
// baseline (839.394 us; speedup 1.0000x reference)
//
#include <hip/hip_runtime.h>
#include <hip/hip_bf16.h>

// Problem constants
static constexpr int N_   = 100000;
static constexpr int E_   = 1600000;
static constexpr int FIN_ = 128;
static constexpr int DIM_ = 32;
static constexpr int NC_  = 40;
static constexpr int BKT    = 32;               // nodes per bucket (N_ % 32 == 0 exactly)
static constexpr int NB_BKT = N_ / BKT;         // 3125 buckets
static constexpr int NCHUNK = 256;              // edge chunks
static constexpr int EPC    = E_ / NCHUNK;      // 6250 edges per chunk (exact)
static constexpr int PROJ_NB = N_ / 32;         // 3125 proj blocks
static constexpr int CS_NB  = (NB_BKT + 7) / 8; // 391 colscan blocks

__device__ __forceinline__ int edge_at(const void* e, int is64, long long i) {
    return is64 ? (int)((const long long*)e)[i] : ((const int*)e)[i];
}

__device__ __forceinline__ float bflo(unsigned u) { return __uint_as_float(u << 16); }
__device__ __forceinline__ float bfhi(unsigned u) { return __uint_as_float(u & 0xffff0000u); }

// Per-block edge dtype detection (reference says int64; JAX x64-off gives int32;
// int32 read as int64 -> garbage high words -> out of [0,N) w.h.p.)
#define DETECT_FLAG(edge, sflag)                                        \
    if (threadIdx.x < 64) {                                             \
        const long long* p_ = (const long long*)(edge);                 \
        long long v_ = p_[threadIdx.x];                                 \
        bool bad_ = (v_ < 0 || v_ >= (long long)N_);                    \
        unsigned long long m_ = __ballot(bad_);                         \
        if (threadIdx.x == 0) sflag = (m_ == 0ull) ? 1 : 0;             \
    }                                                                   \
    __syncthreads();

// ---------------------------------------------------------------------------
// Dispatch 1: blocks [0,256): per-chunk bucket histograms (32-node buckets).
//             blocks [256, 256+3125): proj1 yh = bf16(x @ w1a).
// Independent work fused into one dispatch (chist needs edges; proj needs x).
// proj uses a single k-loop with 4 interleaved accumulators so each LDS
// weight read feeds 4 FMAs (was 1) -> 4x less LDS weight traffic.
// ---------------------------------------------------------------------------
__global__ __launch_bounds__(256) void histproj_kernel(const void* __restrict__ edge,
                                                       int* __restrict__ ghist,
                                                       const float* __restrict__ x,
                                                       const float* __restrict__ w,
                                                       __hip_bfloat16* __restrict__ yh) {
    __shared__ __align__(16) char smem[32768];
    __shared__ int sflag;
    int tid = threadIdx.x;
    if (blockIdx.x < NCHUNK) {
        // ---- chunk histogram ----
        int* lh = (int*)smem;                    // 3125 ints = 12.5 KB
        DETECT_FLAG(edge, sflag)
        for (int i = tid; i < NB_BKT; i += 256) lh[i] = 0;
        __syncthreads();
        int f = sflag;
        int b = blockIdx.x;
        int end = b * EPC + EPC;
        for (int e = b * EPC + tid; e < end; e += 256) {
            int d = edge_at(edge, f, (long long)E_ + e);
            atomicAdd(&lh[d >> 5], 1);           // LDS int atomic
        }
        __syncthreads();
        for (int i = tid; i < NB_BKT; i += 256) ghist[b * NB_BKT + i] = lh[i];
    } else {
        // ---- proj1: 32 nodes per block ----
        float* wsm = (float*)smem;               // 16 KB
        float* xs  = (float*)(smem + 16384);     // 16 KB
        const float4* w4 = (const float4*)w;
        float4* ws4 = (float4*)wsm;
        for (int i = tid; i < FIN_ * DIM_ / 4; i += 256) ws4[i] = w4[i];

        int nodeBase = (blockIdx.x - NCHUNK) * 32;
        const float4* x4 = (const float4*)(x + (size_t)nodeBase * FIN_);
        float4* xs4 = (float4*)xs;
        for (int i = tid; i < 32 * FIN_ / 4; i += 256) xs4[i] = x4[i];
        __syncthreads();

        int d = tid & 31, ns = tid >> 5;
        float acc0 = 0.f, acc1 = 0.f, acc2 = 0.f, acc3 = 0.f;
        const float4* r0 = (const float4*)&xs[(ns +  0) * FIN_];
        const float4* r1 = (const float4*)&xs[(ns +  8) * FIN_];
        const float4* r2 = (const float4*)&xs[(ns + 16) * FIN_];
        const float4* r3 = (const float4*)&xs[(ns + 24) * FIN_];
#pragma unroll
        for (int kc = 0; kc < FIN_ / 4; ++kc) {
            float w0 = wsm[(kc * 4 + 0) * DIM_ + d];
            float w1 = wsm[(kc * 4 + 1) * DIM_ + d];
            float w2 = wsm[(kc * 4 + 2) * DIM_ + d];
            float w3 = wsm[(kc * 4 + 3) * DIM_ + d];
            float4 a;
            a = r0[kc]; acc0 += a.x * w0 + a.y * w1 + a.z * w2 + a.w * w3;
            a = r1[kc]; acc1 += a.x * w0 + a.y * w1 + a.z * w2 + a.w * w3;
            a = r2[kc]; acc2 += a.x * w0 + a.y * w1 + a.z * w2 + a.w * w3;
            a = r3[kc]; acc3 += a.x * w0 + a.y * w1 + a.z * w2 + a.w * w3;
        }
        __hip_bfloat16* yo = yh + (size_t)nodeBase * DIM_ + d;
        yo[(ns +  0) * DIM_] = __float2bfloat16(acc0);
        yo[(ns +  8) * DIM_] = __float2bfloat16(acc1);
        yo[(ns + 16) * DIM_] = __float2bfloat16(acc2);
        yo[(ns + 24) * DIM_] = __float2bfloat16(acc3);
    }
}

// ---------------------------------------------------------------------------
// Dispatch 2: column scans, 8 buckets per block via coalesced LDS tile.
// Outputs gcur[b][k] (CHUNK-major) and bcnt[k]. Last block (ticket) scans
// bucket totals -> bbase.
// ---------------------------------------------------------------------------
__global__ __launch_bounds__(256) void colscan_kernel(const int* __restrict__ ghist,
                                                      int* __restrict__ gcur,
                                                      int* __restrict__ bcnt,
                                                      int* __restrict__ bbase,
                                                      int* __restrict__ done) {
    __shared__ int tile[256 * 9];   // [chunk b][bucket kk], padded
    __shared__ int a[256];
    __shared__ int lastFlag;
    int tid = threadIdx.x;
    int k0 = blockIdx.x * 8;

    {
        int kk = tid & 7, r0 = tid >> 3;
        for (int p = 0; p < 8; ++p) {
            int b = r0 + p * 32;
            int k = k0 + kk;
            tile[b * 9 + kk] = (k < NB_BKT) ? ghist[b * NB_BKT + k] : 0;
        }
    }
    __syncthreads();

    int c = tid >> 5, lane = tid & 31;
    int v[8]; int s = 0;
#pragma unroll
    for (int r = 0; r < 8; ++r) { v[r] = tile[(lane * 8 + r) * 9 + c]; s += v[r]; }
    int incl = s;
#pragma unroll
    for (int off = 1; off < 32; off <<= 1) {
        int u = __shfl_up(incl, off, 32);
        if (lane >= off) incl += u;
    }
    int ex = incl - s;
    int k = k0 + c;
    if (k < NB_BKT) {
        int run = ex;
#pragma unroll
        for (int r = 0; r < 8; ++r) {
            int b = lane * 8 + r;
            gcur[b * NB_BKT + k] = run;
            run += v[r];
        }
        if (lane == 31) bcnt[k] = run;
    }
    __syncthreads();
    if (tid == 0) {
        __threadfence();
        int old = atomicAdd(done, 1);
        lastFlag = (old == CS_NB - 1) ? 1 : 0;
    }
    __syncthreads();
    if (lastFlag) {
        __threadfence();
        constexpr int IPT = (NB_BKT + 255) / 256;   // 13
        int bj[IPT]; int base = tid * IPT; int t = 0;
#pragma unroll
        for (int j = 0; j < IPT; ++j) { int i = base + j; bj[j] = (i < NB_BKT) ? bcnt[i] : 0; t += bj[j]; }
        a[tid] = t;
        __syncthreads();
        for (int off = 1; off < 256; off <<= 1) {
            int u = a[tid] + ((tid >= off) ? a[tid - off] : 0);
            __syncthreads(); a[tid] = u; __syncthreads();
        }
        int g = a[tid] - t;
#pragma unroll
        for (int j = 0; j < IPT; ++j) { int i = base + j; if (i < NB_BKT) bbase[i] = g; g += bj[j]; }
    }
}

// ---------------------------------------------------------------------------
// Dispatch 3: deterministic scatter into bucket regions; cursors in LDS.
// packed[pos] = src | (dst&31)<<17.  No bsort / csr needed anymore.
// ---------------------------------------------------------------------------
__global__ __launch_bounds__(256) void dscatter_kernel(const void* __restrict__ edge,
                                                       const int* __restrict__ bbase,
                                                       const int* __restrict__ gcur,
                                                       int* __restrict__ packed) {
    __shared__ int cur[NB_BKT];
    __shared__ int sflag;
    DETECT_FLAG(edge, sflag)
    int b = blockIdx.x, tid = threadIdx.x;
    for (int k = tid; k < NB_BKT; k += 256) cur[k] = bbase[k] + gcur[b * NB_BKT + k];
    __syncthreads();
    int f = sflag;
    int end = b * EPC + EPC;
    for (int e = b * EPC + tid; e < end; e += 256) {
        int s = edge_at(edge, f, e);
        int d = edge_at(edge, f, (long long)E_ + e);
        int pos = atomicAdd(&cur[d >> 5], 1);     // LDS int atomic
        packed[pos] = s | ((d & 31) << 17);       // N < 2^17
    }
}

// ---------------------------------------------------------------------------
// Edge-parallel gather: lanes map to edges (8 lanes x 8B per 64B row),
// accumulate into LDS f32 via ds_add_f32. Uniform trip count per block
// (no degree divergence), consumes packed directly.
// ---------------------------------------------------------------------------
__device__ __forceinline__ void edge_gather(const int* __restrict__ packed,
                                            const char* __restrict__ vb,
                                            float* __restrict__ A,
                                            int beg, int end, int tid) {
    int slot = tid & 7;
    int loff = slot << 3;   // byte offset within 64B row
    int co   = slot << 2;   // float offset within 32-float row
    int i = beg + (tid >> 3);
    for (; i + 32 < end; i += 64) {
        int p0 = packed[i];
        int p1 = packed[i + 32];
        uint2 u0 = *(const uint2*)(vb + (((size_t)(p0 & 0x1FFFF)) << 6) + loff);
        uint2 u1 = *(const uint2*)(vb + (((size_t)(p1 & 0x1FFFF)) << 6) + loff);
        float* dp0 = &A[(p0 >> 17) * 36 + co];
        atomicAdd(dp0 + 0, bflo(u0.x)); atomicAdd(dp0 + 1, bfhi(u0.x));
        atomicAdd(dp0 + 2, bflo(u0.y)); atomicAdd(dp0 + 3, bfhi(u0.y));
        float* dp1 = &A[(p1 >> 17) * 36 + co];
        atomicAdd(dp1 + 0, bflo(u1.x)); atomicAdd(dp1 + 1, bfhi(u1.x));
        atomicAdd(dp1 + 2, bflo(u1.y)); atomicAdd(dp1 + 3, bfhi(u1.y));
    }
    if (i < end) {
        int p0 = packed[i];
        uint2 u0 = *(const uint2*)(vb + (((size_t)(p0 & 0x1FFFF)) << 6) + loff);
        float* dp0 = &A[(p0 >> 17) * 36 + co];
        atomicAdd(dp0 + 0, bflo(u0.x)); atomicAdd(dp0 + 1, bfhi(u0.x));
        atomicAdd(dp0 + 2, bflo(u0.y)); atomicAdd(dp0 + 3, bfhi(u0.y));
    }
}

// ---------------------------------------------------------------------------
// Dispatch 4: per-bucket (32 nodes) fused layer 1.
// gather -> u=relu(agg+y+b1a) -> hb=bn1(relu(u@w1b+b1b)) -> zh=bf16(hb@w2a).
// All dot stages use a single k-loop with 4 interleaved row-accumulators:
// each weight LDS read feeds 4 FMAs; activation rows are 16B-aligned (pad 36)
// and read as float4.
// ---------------------------------------------------------------------------
__global__ __launch_bounds__(256, 8) void aggmlp1_kernel(const int* __restrict__ bbase,
                                                         const int* __restrict__ bcnt,
                                                         const int* __restrict__ packed,
                                                         const __hip_bfloat16* __restrict__ yh,
                                                         const float* __restrict__ b1a,
                                                         const float* __restrict__ w1b,
                                                         const float* __restrict__ b1b,
                                                         const float* __restrict__ g1,
                                                         const float* __restrict__ be1,
                                                         const float* __restrict__ m1,
                                                         const float* __restrict__ v1,
                                                         const float* __restrict__ w2a,
                                                         __hip_bfloat16* __restrict__ zh) {
    __shared__ float A[32 * 36];
    __shared__ float B[32 * 36];
    __shared__ float w1s[DIM_ * DIM_];
    __shared__ float w2s[DIM_ * DIM_];
    int tid = threadIdx.x;
    for (int i = tid; i < 32 * 36; i += 256) A[i] = 0.f;
    for (int i = tid; i < DIM_ * DIM_; i += 256) { w1s[i] = w1b[i]; w2s[i] = w2a[i]; }
    __syncthreads();

    int b = blockIdx.x;
    int beg = bbase[b], end = beg + bcnt[b];
    edge_gather(packed, (const char*)yh, A, beg, end, tid);
    __syncthreads();

    int d = tid & 31, ng = tid >> 5;
    size_t gbase = (size_t)b * 32 * DIM_;

    // u = relu(agg + y + b1a)
    {
        float bv = b1a[d];
#pragma unroll
        for (int r = 0; r < 4; ++r) {
            int n = r * 8 + ng;
            float yv = __bfloat162float(yh[gbase + n * DIM_ + d]);
            A[n * 36 + d] = fmaxf(A[n * 36 + d] + yv + bv, 0.f);
        }
    }
    __syncthreads();

    float sc1 = g1[d] * rsqrtf(v1[d] + 1e-5f);
    float sh1 = be1[d] - m1[d] * sc1;

    // hb = bn1(relu(u @ w1b + b1b))
    {
        float s0 = b1b[d], s1 = s0, s2 = s0, s3 = s0;
        const float4* r0 = (const float4*)&A[(ng +  0) * 36];
        const float4* r1 = (const float4*)&A[(ng +  8) * 36];
        const float4* r2 = (const float4*)&A[(ng + 16) * 36];
        const float4* r3 = (const float4*)&A[(ng + 24) * 36];
#pragma unroll
        for (int kc = 0; kc < 8; ++kc) {
            float w0 = w1s[(kc * 4 + 0) * DIM_ + d];
            float w1 = w1s[(kc * 4 + 1) * DIM_ + d];
            float w2 = w1s[(kc * 4 + 2) * DIM_ + d];
            float w3 = w1s[(kc * 4 + 3) * DIM_ + d];
            float4 a;
            a = r0[kc]; s0 += a.x * w0 + a.y * w1 + a.z * w2 + a.w * w3;
            a = r1[kc]; s1 += a.x * w0 + a.y * w1 + a.z * w2 + a.w * w3;
            a = r2[kc]; s2 += a.x * w0 + a.y * w1 + a.z * w2 + a.w * w3;
            a = r3[kc]; s3 += a.x * w0 + a.y * w1 + a.z * w2 + a.w * w3;
        }
        B[(ng +  0) * 36 + d] = fmaxf(s0, 0.f) * sc1 + sh1;
        B[(ng +  8) * 36 + d] = fmaxf(s1, 0.f) * sc1 + sh1;
        B[(ng + 16) * 36 + d] = fmaxf(s2, 0.f) * sc1 + sh1;
        B[(ng + 24) * 36 + d] = fmaxf(s3, 0.f) * sc1 + sh1;
    }
    __syncthreads();

    // z = hb @ w2a -> bf16
    {
        float s0 = 0.f, s1 = 0.f, s2 = 0.f, s3 = 0.f;
        const float4* r0 = (const float4*)&B[(ng +  0) * 36];
        const float4* r1 = (const float4*)&B[(ng +  8) * 36];
        const float4* r2 = (const float4*)&B[(ng + 16) * 36];
        const float4* r3 = (const float4*)&B[(ng + 24) * 36];
#pragma unroll
        for (int kc = 0; kc < 8; ++kc) {
            float w0 = w2s[(kc * 4 + 0) * DIM_ + d];
            float w1 = w2s[(kc * 4 + 1) * DIM_ + d];
            float w2 = w2s[(kc * 4 + 2) * DIM_ + d];
            float w3 = w2s[(kc * 4 + 3) * DIM_ + d];
            float4 a;
            a = r0[kc]; s0 += a.x * w0 + a.y * w1 + a.z * w2 + a.w * w3;
            a = r1[kc]; s1 += a.x * w0 + a.y * w1 + a.z * w2 + a.w * w3;
            a = r2[kc]; s2 += a.x * w0 + a.y * w1 + a.z * w2 + a.w * w3;
            a = r3[kc]; s3 += a.x * w0 + a.y * w1 + a.z * w2 + a.w * w3;
        }
        zh[gbase + (ng +  0) * DIM_ + d] = __float2bfloat16(s0);
        zh[gbase + (ng +  8) * DIM_ + d] = __float2bfloat16(s1);
        zh[gbase + (ng + 16) * DIM_ + d] = __float2bfloat16(s2);
        zh[gbase + (ng + 24) * DIM_ + d] = __float2bfloat16(s3);
    }
}

// ---------------------------------------------------------------------------
// Dispatch 5: per-bucket fused layer 2 + head.
// gather -> u2=relu(agg+z+b2a) -> hb=bn2(u2@w2b+b2b) -> f=relu(hb@fc1w+f1b)
// -> logits -> log_softmax. Same interleaved-accumulator dot structure.
// ---------------------------------------------------------------------------
__global__ __launch_bounds__(256, 8) void aggmlp2_kernel(const int* __restrict__ bbase,
                                                         const int* __restrict__ bcnt,
                                                         const int* __restrict__ packed,
                                                         const __hip_bfloat16* __restrict__ zh,
                                                         const float* __restrict__ b2a,
                                                         const float* __restrict__ w2b,
                                                         const float* __restrict__ b2b,
                                                         const float* __restrict__ g2,
                                                         const float* __restrict__ be2,
                                                         const float* __restrict__ m2,
                                                         const float* __restrict__ v2,
                                                         const float* __restrict__ f1w,
                                                         const float* __restrict__ f1b,
                                                         const float* __restrict__ f2w,
                                                         const float* __restrict__ f2b,
                                                         float* __restrict__ out) {
    __shared__ float A[32 * 36];
    __shared__ float BC[DIM_ * NC_];   // hb tile (32x36=1152 used) then wC (1280 floats)
    __shared__ float wA[DIM_ * DIM_];
    __shared__ float wB[DIM_ * DIM_];
    int tid = threadIdx.x;
    for (int i = tid; i < 32 * 36; i += 256) A[i] = 0.f;
    for (int i = tid; i < DIM_ * DIM_; i += 256) { wA[i] = w2b[i]; wB[i] = f1w[i]; }
    __syncthreads();

    int b = blockIdx.x;
    int beg = bbase[b], end = beg + bcnt[b];
    edge_gather(packed, (const char*)zh, A, beg, end, tid);
    __syncthreads();

    int d = tid & 31, ng = tid >> 5;
    size_t gbase = (size_t)b * 32 * DIM_;

    // u2 = relu(agg + z + b2a)
    {
        float bv = b2a[d];
#pragma unroll
        for (int r = 0; r < 4; ++r) {
            int n = r * 8 + ng;
            float zv = __bfloat162float(zh[gbase + n * DIM_ + d]);
            A[n * 36 + d] = fmaxf(A[n * 36 + d] + zv + bv, 0.f);
        }
    }
    __syncthreads();

    float sc2 = g2[d] * rsqrtf(v2[d] + 1e-5f);
    float sh2 = be2[d] - m2[d] * sc2;

    // hb = bn2(u2 @ w2b + b2b)   (no relu between conv2 and bn2)
    {
        float s0 = b2b[d], s1 = s0, s2 = s0, s3 = s0;
        const float4* r0 = (const float4*)&A[(ng +  0) * 36];
        const float4* r1 = (const float4*)&A[(ng +  8) * 36];
        const float4* r2 = (const float4*)&A[(ng + 16) * 36];
        const float4* r3 = (const float4*)&A[(ng + 24) * 36];
#pragma unroll
        for (int kc = 0; kc < 8; ++kc) {
            float w0 = wA[(kc * 4 + 0) * DIM_ + d];
            float w1 = wA[(kc * 4 + 1) * DIM_ + d];
            float w2 = wA[(kc * 4 + 2) * DIM_ + d];
            float w3 = wA[(kc * 4 + 3) * DIM_ + d];
            float4 a;
            a = r0[kc]; s0 += a.x * w0 + a.y * w1 + a.z * w2 + a.w * w3;
            a = r1[kc]; s1 += a.x * w0 + a.y * w1 + a.z * w2 + a.w * w3;
            a = r2[kc]; s2 += a.x * w0 + a.y * w1 + a.z * w2 + a.w * w3;
            a = r3[kc]; s3 += a.x * w0 + a.y * w1 + a.z * w2 + a.w * w3;
        }
        BC[(ng +  0) * 36 + d] = s0 * sc2 + sh2;
        BC[(ng +  8) * 36 + d] = s1 * sc2 + sh2;
        BC[(ng + 16) * 36 + d] = s2 * sc2 + sh2;
        BC[(ng + 24) * 36 + d] = s3 * sc2 + sh2;
    }
    __syncthreads();

    // f = relu(hb @ fc1w + fc1b) -> overwrite A (u2 dead)
    {
        float s0 = f1b[d], s1 = s0, s2 = s0, s3 = s0;
        const float4* r0 = (const float4*)&BC[(ng +  0) * 36];
        const float4* r1 = (const float4*)&BC[(ng +  8) * 36];
        const float4* r2 = (const float4*)&BC[(ng + 16) * 36];
        const float4* r3 = (const float4*)&BC[(ng + 24) * 36];
#pragma unroll
        for (int kc = 0; kc < 8; ++kc) {
            float w0 = wB[(kc * 4 + 0) * DIM_ + d];
            float w1 = wB[(kc * 4 + 1) * DIM_ + d];
            float w2 = wB[(kc * 4 + 2) * DIM_ + d];
            float w3 = wB[(kc * 4 + 3) * DIM_ + d];
            float4 a;
            a = r0[kc]; s0 += a.x * w0 + a.y * w1 + a.z * w2 + a.w * w3;
            a = r1[kc]; s1 += a.x * w0 + a.y * w1 + a.z * w2 + a.w * w3;
            a = r2[kc]; s2 += a.x * w0 + a.y * w1 + a.z * w2 + a.w * w3;
            a = r3[kc]; s3 += a.x * w0 + a.y * w1 + a.z * w2 + a.w * w3;
        }
        A[(ng +  0) * 36 + d] = fmaxf(s0, 0.f);
        A[(ng +  8) * 36 + d] = fmaxf(s1, 0.f);
        A[(ng + 16) * 36 + d] = fmaxf(s2, 0.f);
        A[(ng + 24) * 36 + d] = fmaxf(s3, 0.f);
    }
    __syncthreads();
    // hb dead -> load wC over BC
    for (int i = tid; i < DIM_ * NC_; i += 256) BC[i] = f2w[i];
    __syncthreads();

    // logits + log_softmax (thread d owns col d and col 32+(d&7))
    int c2 = 32 + (d & 7);
    float l00 = f2b[d], l01 = l00, l02 = l00, l03 = l00;
    float cb = f2b[c2];
    float l10 = cb, l11 = cb, l12 = cb, l13 = cb;
    {
        const float4* r0 = (const float4*)&A[(ng +  0) * 36];
        const float4* r1 = (const float4*)&A[(ng +  8) * 36];
        const float4* r2 = (const float4*)&A[(ng + 16) * 36];
        const float4* r3 = (const float4*)&A[(ng + 24) * 36];
#pragma unroll
        for (int kc = 0; kc < 8; ++kc) {
            float wa0 = BC[(kc * 4 + 0) * NC_ + d];
            float wa1 = BC[(kc * 4 + 1) * NC_ + d];
            float wa2 = BC[(kc * 4 + 2) * NC_ + d];
            float wa3 = BC[(kc * 4 + 3) * NC_ + d];
            float wb0 = BC[(kc * 4 + 0) * NC_ + c2];
            float wb1 = BC[(kc * 4 + 1) * NC_ + c2];
            float wb2 = BC[(kc * 4 + 2) * NC_ + c2];
            float wb3 = BC[(kc * 4 + 3) * NC_ + c2];
            float4 a;
            a = r0[kc];
            l00 += a.x * wa0 + a.y * wa1 + a.z * wa2 + a.w * wa3;
            l10 += a.x * wb0 + a.y * wb1 + a.z * wb2 + a.w * wb3;
            a = r1[kc];
            l01 += a.x * wa0 + a.y * wa1 + a.z * wa2 + a.w * wa3;
            l11 += a.x * wb0 + a.y * wb1 + a.z * wb2 + a.w * wb3;
            a = r2[kc];
            l02 += a.x * wa0 + a.y * wa1 + a.z * wa2 + a.w * wa3;
            l12 += a.x * wb0 + a.y * wb1 + a.z * wb2 + a.w * wb3;
            a = r3[kc];
            l03 += a.x * wa0 + a.y * wa1 + a.z * wa2 + a.w * wa3;
            l13 += a.x * wb0 + a.y * wb1 + a.z * wb2 + a.w * wb3;
        }
    }
#pragma unroll
    for (int r = 0; r < 4; ++r) {
        float l0 = (r == 0) ? l00 : (r == 1) ? l01 : (r == 2) ? l02 : l03;
        float l1 = (r == 0) ? l10 : (r == 1) ? l11 : (r == 2) ? l12 : l13;
        int n = r * 8 + ng;
        float mx = fmaxf(l0, l1);
#pragma unroll
        for (int off = 16; off; off >>= 1) mx = fmaxf(mx, __shfl_xor(mx, off));
        float se = __expf(l0 - mx) + ((d < 8) ? __expf(l1 - mx) : 0.f);
#pragma unroll
        for (int off = 16; off; off >>= 1) se += __shfl_xor(se, off);
        float lse = mx + __logf(se);
        size_t ob = (size_t)(b * 32 + n) * NC_;
        out[ob + d] = l0 - lse;
        if (d < 8) out[ob + 32 + d] = l1 - lse;
    }
}

// ---------------------------------------------------------------------------
extern "C" void kernel_launch(void* const* d_in, const int* in_sizes, int n_in,
                              void* d_out, int out_size, void* d_ws, size_t ws_size,
                              hipStream_t stream) {
    const float* x   = (const float*)d_in[0];
    const void*  edg = d_in[1];
    const float* w1a = (const float*)d_in[2];
    const float* b1a = (const float*)d_in[3];
    const float* w1b = (const float*)d_in[4];
    const float* b1b = (const float*)d_in[5];
    const float* w2a = (const float*)d_in[6];
    const float* b2a = (const float*)d_in[7];
    const float* w2b = (const float*)d_in[8];
    const float* b2b = (const float*)d_in[9];
    const float* g1  = (const float*)d_in[10];
    const float* be1 = (const float*)d_in[11];
    const float* m1  = (const float*)d_in[12];
    const float* v1  = (const float*)d_in[13];
    const float* g2  = (const float*)d_in[14];
    const float* be2 = (const float*)d_in[15];
    const float* m2  = (const float*)d_in[16];
    const float* v2  = (const float*)d_in[17];
    const float* f1w = (const float*)d_in[18];
    const float* f1b = (const float*)d_in[19];
    const float* f2w = (const float*)d_in[20];
    const float* f2b = (const float*)d_in[21];
    float* out = (float*)d_out;

    // Workspace layout (byte offsets, 128B-aligned)
    char* ws = (char*)d_ws;
    int* done   = (int*)ws;                      // 4 B (memset each launch)
    int* bcnt   = (int*)(ws + 256);              // 3125 ints
    int* bbase  = (int*)(ws + 12800);            // 3125 ints
    int* ghist  = (int*)(ws + 25344);            // 256*3125 ints = 3.2 MB
    int* gcur   = (int*)(ws + 3225344);          // 256*3125 ints (chunk-major)
    int* packed = (int*)(ws + 6425344);          // E ints
    __hip_bfloat16* yh = (__hip_bfloat16*)(ws + 12825344);  // N*DIM bf16
    __hip_bfloat16* zh = (__hip_bfloat16*)(ws + 19225344);  // N*DIM bf16

    hipMemsetAsync(done, 0, 4, stream);

    // ---- Build bucket-partitioned edge list (no bsort/csr) ∥ proj ----
    histproj_kernel<<<NCHUNK + PROJ_NB, 256, 0, stream>>>(edg, ghist, x, w1a, yh);
    colscan_kernel<<<CS_NB, 256, 0, stream>>>(ghist, gcur, bcnt, bbase, done);
    dscatter_kernel<<<NCHUNK, 256, 0, stream>>>(edg, bbase, gcur, packed);

    // ---- Layer 1 (proj folded pre-aggregation) ----
    aggmlp1_kernel<<<NB_BKT, 256, 0, stream>>>(bbase, bcnt, packed, yh, b1a, w1b, b1b,
                                               g1, be1, m1, v1, w2a, zh);

    // ---- Layer 2 + head (w2a folded pre-aggregation) ----
    aggmlp2_kernel<<<NB_BKT, 256, 0, stream>>>(bbase, bcnt, packed, zh, b2a, w2b, b2b,
                                               g2, be2, m2, v2, f1w, f1b,
                                               f2w, f2b, out);
}

// Round 2
// 312.600 us; speedup vs baseline: 2.6852x; 2.6852x over previous
//
#include <hip/hip_runtime.h>
#include <hip/hip_bf16.h>

// Problem constants
static constexpr int N_   = 100000;
static constexpr int E_   = 1600000;
static constexpr int FIN_ = 128;
static constexpr int DIM_ = 32;
static constexpr int NC_  = 40;
static constexpr int NB_BKT = (N_ + 127) / 128;   // 782 buckets of 128 dst nodes
static constexpr int NCHUNK = 256;                // edge chunks
static constexpr int EPC    = E_ / NCHUNK;        // 6250 edges per chunk (exact)
static constexpr int PROJ_NB = N_ / 32;           // 3125 proj blocks
static constexpr int CS_NB  = (NB_BKT + 7) / 8;   // 98 colscan blocks

__device__ __forceinline__ int edge_at(const void* e, int is64, long long i) {
    return is64 ? (int)((const long long*)e)[i] : ((const int*)e)[i];
}

__device__ __forceinline__ float bflo(unsigned u) { return __uint_as_float(u << 16); }
__device__ __forceinline__ float bfhi(unsigned u) { return __uint_as_float(u & 0xffff0000u); }

// Per-block edge dtype detection (reference says int64; JAX x64-off gives int32;
// int32 read as int64 -> garbage high words -> out of [0,N) w.h.p.)
#define DETECT_FLAG(edge, sflag)                                        \
    if (threadIdx.x < 64) {                                             \
        const long long* p_ = (const long long*)(edge);                 \
        long long v_ = p_[threadIdx.x];                                 \
        bool bad_ = (v_ < 0 || v_ >= (long long)N_);                    \
        unsigned long long m_ = __ballot(bad_);                         \
        if (threadIdx.x == 0) sflag = (m_ == 0ull) ? 1 : 0;             \
    }                                                                   \
    __syncthreads();

// ---------------------------------------------------------------------------
// Build 1: per-chunk bucket histogram in LDS -> ghist[b][k] (coalesced write)
// ---------------------------------------------------------------------------
__global__ __launch_bounds__(256) void chist_kernel(const void* __restrict__ edge,
                                                    int* __restrict__ ghist) {
    __shared__ int lh[NB_BKT];
    __shared__ int sflag;
    DETECT_FLAG(edge, sflag)
    for (int i = threadIdx.x; i < NB_BKT; i += 256) lh[i] = 0;
    __syncthreads();
    int f = sflag;
    int b = blockIdx.x;
    int end = b * EPC + EPC;
    for (int e = b * EPC + threadIdx.x; e < end; e += 256) {
        int d = edge_at(edge, f, (long long)E_ + e);
        atomicAdd(&lh[d >> 7], 1);           // LDS int atomic
    }
    __syncthreads();
    for (int i = threadIdx.x; i < NB_BKT; i += 256) ghist[b * NB_BKT + i] = lh[i];
}

// ---------------------------------------------------------------------------
// Build 2: column scans, 8 buckets per block via coalesced LDS tile.
// Outputs gcur[b][k] (CHUNK-major -> dscatter reads a coalesced row) and
// bcnt[k]. Last block (ticket) scans bucket totals -> bbase + offs[N].
// ---------------------------------------------------------------------------
__global__ __launch_bounds__(256) void colscan_kernel(const int* __restrict__ ghist,
                                                      int* __restrict__ gcur,
                                                      int* __restrict__ bcnt,
                                                      int* __restrict__ bbase,
                                                      int* __restrict__ offs,
                                                      int* __restrict__ done) {
    __shared__ int tile[256 * 9];   // [chunk b][bucket kk], padded
    __shared__ int a[256];
    __shared__ int lastFlag;
    int tid = threadIdx.x;
    int k0 = blockIdx.x * 8;

    // coalesced-ish load: 8 lanes per chunk-row (32B of one line), 32 rows/pass
    {
        int kk = tid & 7, r0 = tid >> 3;
        for (int p = 0; p < 8; ++p) {
            int b = r0 + p * 32;
            int k = k0 + kk;
            tile[b * 9 + kk] = (k < NB_BKT) ? ghist[b * NB_BKT + k] : 0;
        }
    }
    __syncthreads();

    // scan each of 8 columns over 256 chunks: half-wave (32 lanes) per column,
    // 8 chunks per lane, shuffle-scan of lane sums.
    int c = tid >> 5, lane = tid & 31;
    int v[8]; int s = 0;
#pragma unroll
    for (int r = 0; r < 8; ++r) { v[r] = tile[(lane * 8 + r) * 9 + c]; s += v[r]; }
    int incl = s;
#pragma unroll
    for (int off = 1; off < 32; off <<= 1) {
        int u = __shfl_up(incl, off, 32);
        if (lane >= off) incl += u;
    }
    int ex = incl - s;
    int k = k0 + c;
    if (k < NB_BKT) {
        int run = ex;
#pragma unroll
        for (int r = 0; r < 8; ++r) {
            int b = lane * 8 + r;
            gcur[b * NB_BKT + k] = run;     // exclusive prefix for (chunk b, bucket k)
            run += v[r];
        }
        if (lane == 31) bcnt[k] = run;      // bucket total
    }
    __syncthreads();
    if (tid == 0) {
        __threadfence();                    // release gcur/bcnt before ticket
        int old = atomicAdd(done, 1);
        lastFlag = (old == CS_NB - 1) ? 1 : 0;
    }
    __syncthreads();
    if (lastFlag) {
        __threadfence();                    // acquire other blocks' bcnt
        int b4[4]; int base4 = tid * 4; int t = 0;
#pragma unroll
        for (int j = 0; j < 4; ++j) { int i = base4 + j; b4[j] = (i < NB_BKT) ? bcnt[i] : 0; t += b4[j]; }
        a[tid] = t;
        __syncthreads();
        for (int off = 1; off < 256; off <<= 1) {
            int u = a[tid] + ((tid >= off) ? a[tid - off] : 0);
            __syncthreads(); a[tid] = u; __syncthreads();
        }
        int g = a[tid] - t;
#pragma unroll
        for (int j = 0; j < 4; ++j) { int i = base4 + j; if (i < NB_BKT) bbase[i] = g; g += b4[j]; }
        if (tid == 255) offs[N_] = a[255];  // == E_
    }
}

// ---------------------------------------------------------------------------
// Build 3: deterministic scatter into bucket regions; cursors in LDS.
// Cursor init is a coalesced 3 KB row read (gcur is chunk-major).
// ---------------------------------------------------------------------------
__global__ __launch_bounds__(256) void dscatter_kernel(const void* __restrict__ edge,
                                                       const int* __restrict__ bbase,
                                                       const int* __restrict__ gcur,
                                                       int* __restrict__ packed) {
    __shared__ int cur[NB_BKT];
    __shared__ int sflag;
    DETECT_FLAG(edge, sflag)
    int b = blockIdx.x, tid = threadIdx.x;
    for (int k = tid; k < NB_BKT; k += 256) cur[k] = bbase[k] + gcur[b * NB_BKT + k];
    __syncthreads();
    int f = sflag;
    int end = b * EPC + EPC;
    for (int e = b * EPC + tid; e < end; e += 256) {
        int s = edge_at(edge, f, e);
        int d = edge_at(edge, f, (long long)E_ + e);
        int pos = atomicAdd(&cur[d >> 7], 1);     // LDS int atomic
        packed[pos] = s | ((d & 127) << 17);      // N < 2^17
    }
}

// ---------------------------------------------------------------------------
// Build 4 ∥ proj: blocks [0,782): per-bucket counting sort -> offs[] + csr[];
// blocks [782, 782+3125): yh = bf16(x @ w1a). Independent work, one dispatch.
// proj: single k-loop, 4 interleaved row accumulators -> each LDS weight read
// feeds 4 FMAs (was 1); activation rows read as float4.
// ---------------------------------------------------------------------------
__global__ __launch_bounds__(256) void fat_kernel(const int* __restrict__ bcnt,
                                                  const int* __restrict__ bbase,
                                                  const int* __restrict__ packed,
                                                  int* __restrict__ offs,
                                                  int* __restrict__ csr,
                                                  const float* __restrict__ x,
                                                  const float* __restrict__ w,
                                                  __hip_bfloat16* __restrict__ yh) {
    __shared__ __align__(16) char smem[32768];
    int tid = threadIdx.x;
    if (blockIdx.x < NB_BKT) {
        // ---- bsort ----
        int* c   = (int*)smem;
        int* cur = (int*)smem + 128;
        int b = blockIdx.x;
        int beg = bbase[b], cnt = bcnt[b];
        if (tid < 128) c[tid] = 0;
        __syncthreads();
        for (int i = tid; i < cnt; i += 256)
            atomicAdd(&c[packed[beg + i] >> 17], 1);
        __syncthreads();
        int myv = (tid < 128) ? c[tid] : 0;
        for (int off = 1; off < 128; off <<= 1) {
            int t = 0;
            if (tid < 128) t = c[tid] + ((tid >= off) ? c[tid - off] : 0);
            __syncthreads();
            if (tid < 128) c[tid] = t;
            __syncthreads();
        }
        if (tid < 128) {
            int ex = c[tid] - myv;
            cur[tid] = ex;
            int node = b * 128 + tid;
            if (node < N_) offs[node] = beg + ex;
        }
        __syncthreads();
        for (int i = tid; i < cnt; i += 256) {
            int v = packed[beg + i];
            int p = atomicAdd(&cur[v >> 17], 1);
            csr[beg + p] = v & 0x1FFFF;
        }
    } else {
        // ---- proj1: 32 nodes per block, interleaved accumulators ----
        float* wsm = (float*)smem;               // 16 KB
        float* xs  = (float*)(smem + 16384);     // 16 KB
        const float4* w4 = (const float4*)w;
        float4* ws4 = (float4*)wsm;
        for (int i = tid; i < FIN_ * DIM_ / 4; i += 256) ws4[i] = w4[i];

        int nodeBase = (blockIdx.x - NB_BKT) * 32;
        const float4* x4 = (const float4*)(x + (size_t)nodeBase * FIN_);
        float4* xs4 = (float4*)xs;
        for (int i = tid; i < 32 * FIN_ / 4; i += 256) xs4[i] = x4[i];
        __syncthreads();

        int d = tid & 31, ns = tid >> 5;
        float acc0 = 0.f, acc1 = 0.f, acc2 = 0.f, acc3 = 0.f;
        const float4* r0 = (const float4*)&xs[(ns +  0) * FIN_];
        const float4* r1 = (const float4*)&xs[(ns +  8) * FIN_];
        const float4* r2 = (const float4*)&xs[(ns + 16) * FIN_];
        const float4* r3 = (const float4*)&xs[(ns + 24) * FIN_];
#pragma unroll
        for (int kc = 0; kc < FIN_ / 4; ++kc) {
            float w0 = wsm[(kc * 4 + 0) * DIM_ + d];
            float w1 = wsm[(kc * 4 + 1) * DIM_ + d];
            float w2 = wsm[(kc * 4 + 2) * DIM_ + d];
            float w3 = wsm[(kc * 4 + 3) * DIM_ + d];
            float4 a;
            a = r0[kc]; acc0 += a.x * w0 + a.y * w1 + a.z * w2 + a.w * w3;
            a = r1[kc]; acc1 += a.x * w0 + a.y * w1 + a.z * w2 + a.w * w3;
            a = r2[kc]; acc2 += a.x * w0 + a.y * w1 + a.z * w2 + a.w * w3;
            a = r3[kc]; acc3 += a.x * w0 + a.y * w1 + a.z * w2 + a.w * w3;
        }
        __hip_bfloat16* yo = yh + (size_t)nodeBase * DIM_ + d;
        yo[(ns +  0) * DIM_] = __float2bfloat16(acc0);
        yo[(ns +  8) * DIM_] = __float2bfloat16(acc1);
        yo[(ns + 16) * DIM_] = __float2bfloat16(acc2);
        yo[(ns + 24) * DIM_] = __float2bfloat16(acc3);
    }
}

// ---------------------------------------------------------------------------
// Gather (R6-proven config): 8 lanes x 8B (uint2) per 64B row, 4-wide unroll.
// Node-parallel, per-lane private accumulators — NO atomics.
// ---------------------------------------------------------------------------
__device__ __forceinline__ void gather_row(const int* __restrict__ csr,
                                           const char* __restrict__ vb,
                                           int beg, int end, int loff,
                                           float& a0, float& a1, float& a2, float& a3) {
    int i = beg;
    for (; i + 3 < end; i += 4) {
        int s0 = csr[i], s1 = csr[i + 1], s2 = csr[i + 2], s3 = csr[i + 3];
        uint2 u0 = *(const uint2*)(vb + (((size_t)s0) << 6) + loff);
        uint2 u1 = *(const uint2*)(vb + (((size_t)s1) << 6) + loff);
        uint2 u2 = *(const uint2*)(vb + (((size_t)s2) << 6) + loff);
        uint2 u3 = *(const uint2*)(vb + (((size_t)s3) << 6) + loff);
        a0 += (bflo(u0.x) + bflo(u1.x)) + (bflo(u2.x) + bflo(u3.x));
        a1 += (bfhi(u0.x) + bfhi(u1.x)) + (bfhi(u2.x) + bfhi(u3.x));
        a2 += (bflo(u0.y) + bflo(u1.y)) + (bflo(u2.y) + bflo(u3.y));
        a3 += (bfhi(u0.y) + bfhi(u1.y)) + (bfhi(u2.y) + bfhi(u3.y));
    }
    for (; i < end; ++i) {
        int s0 = csr[i];
        uint2 u0 = *(const uint2*)(vb + (((size_t)s0) << 6) + loff);
        a0 += bflo(u0.x); a1 += bfhi(u0.x); a2 += bflo(u0.y); a3 += bfhi(u0.y);
    }
}

// ---------------------------------------------------------------------------
// Fused 1: 32 nodes/block, dual A/B LDS buffers (stride 36 -> 16B-aligned rows).
// gather -> u=relu(agg+y+b1a) -> hb=bn1(relu(u@w1b+b1b)) -> zh=bf16(hb@w2a).
// Dot stages: single k-loop, 4 interleaved row accumulators, float4 row reads.
// ---------------------------------------------------------------------------
__global__ __launch_bounds__(256) void aggmlp1_kernel(const int* __restrict__ offs,
                                                      const int* __restrict__ csr,
                                                      const __hip_bfloat16* __restrict__ yh,
                                                      const float* __restrict__ b1a,
                                                      const float* __restrict__ w1b,
                                                      const float* __restrict__ b1b,
                                                      const float* __restrict__ g1,
                                                      const float* __restrict__ be1,
                                                      const float* __restrict__ m1,
                                                      const float* __restrict__ v1,
                                                      const float* __restrict__ w2a,
                                                      __hip_bfloat16* __restrict__ zh) {
    __shared__ __align__(16) float A[32 * 36];
    __shared__ __align__(16) float B[32 * 36];
    __shared__ float w1s[DIM_ * DIM_];
    __shared__ float w2s[DIM_ * DIM_];
    int tid = threadIdx.x;
    for (int i = tid; i < DIM_ * DIM_; i += 256) { w1s[i] = w1b[i]; w2s[i] = w2a[i]; }

    int nl = tid >> 3, lane = tid & 7;
    int node = blockIdx.x * 32 + nl;
    int beg = offs[node], end = offs[node + 1];
    float a0 = 0.f, a1 = 0.f, a2 = 0.f, a3 = 0.f;
    gather_row(csr, (const char*)yh, beg, end, lane << 3, a0, a1, a2, a3);
    {
        float* p = &A[nl * 36 + lane * 4];
        p[0] = a0; p[1] = a1; p[2] = a2; p[3] = a3;
    }
    __syncthreads();

    int d = tid & 31, ng = tid >> 5;
    size_t gbase = (size_t)blockIdx.x * 32 * DIM_;

    // u = relu(agg + y + b1a)
    {
        float bv = b1a[d];
#pragma unroll
        for (int r = 0; r < 4; ++r) {
            int n = r * 8 + ng;
            float yv = __bfloat162float(yh[gbase + n * DIM_ + d]);
            A[n * 36 + d] = fmaxf(A[n * 36 + d] + yv + bv, 0.f);
        }
    }
    __syncthreads();

    float sc1 = g1[d] * rsqrtf(v1[d] + 1e-5f);
    float sh1 = be1[d] - m1[d] * sc1;

    // hb = bn1(relu(u @ w1b + b1b))
    {
        float s0 = b1b[d], s1 = s0, s2 = s0, s3 = s0;
        const float4* r0 = (const float4*)&A[(ng +  0) * 36];
        const float4* r1 = (const float4*)&A[(ng +  8) * 36];
        const float4* r2 = (const float4*)&A[(ng + 16) * 36];
        const float4* r3 = (const float4*)&A[(ng + 24) * 36];
#pragma unroll
        for (int kc = 0; kc < 8; ++kc) {
            float w0 = w1s[(kc * 4 + 0) * DIM_ + d];
            float w1 = w1s[(kc * 4 + 1) * DIM_ + d];
            float w2 = w1s[(kc * 4 + 2) * DIM_ + d];
            float w3 = w1s[(kc * 4 + 3) * DIM_ + d];
            float4 a;
            a = r0[kc]; s0 += a.x * w0 + a.y * w1 + a.z * w2 + a.w * w3;
            a = r1[kc]; s1 += a.x * w0 + a.y * w1 + a.z * w2 + a.w * w3;
            a = r2[kc]; s2 += a.x * w0 + a.y * w1 + a.z * w2 + a.w * w3;
            a = r3[kc]; s3 += a.x * w0 + a.y * w1 + a.z * w2 + a.w * w3;
        }
        B[(ng +  0) * 36 + d] = fmaxf(s0, 0.f) * sc1 + sh1;
        B[(ng +  8) * 36 + d] = fmaxf(s1, 0.f) * sc1 + sh1;
        B[(ng + 16) * 36 + d] = fmaxf(s2, 0.f) * sc1 + sh1;
        B[(ng + 24) * 36 + d] = fmaxf(s3, 0.f) * sc1 + sh1;
    }
    __syncthreads();

    // z = hb @ w2a -> bf16
    {
        float s0 = 0.f, s1 = 0.f, s2 = 0.f, s3 = 0.f;
        const float4* r0 = (const float4*)&B[(ng +  0) * 36];
        const float4* r1 = (const float4*)&B[(ng +  8) * 36];
        const float4* r2 = (const float4*)&B[(ng + 16) * 36];
        const float4* r3 = (const float4*)&B[(ng + 24) * 36];
#pragma unroll
        for (int kc = 0; kc < 8; ++kc) {
            float w0 = w2s[(kc * 4 + 0) * DIM_ + d];
            float w1 = w2s[(kc * 4 + 1) * DIM_ + d];
            float w2 = w2s[(kc * 4 + 2) * DIM_ + d];
            float w3 = w2s[(kc * 4 + 3) * DIM_ + d];
            float4 a;
            a = r0[kc]; s0 += a.x * w0 + a.y * w1 + a.z * w2 + a.w * w3;
            a = r1[kc]; s1 += a.x * w0 + a.y * w1 + a.z * w2 + a.w * w3;
            a = r2[kc]; s2 += a.x * w0 + a.y * w1 + a.z * w2 + a.w * w3;
            a = r3[kc]; s3 += a.x * w0 + a.y * w1 + a.z * w2 + a.w * w3;
        }
        zh[gbase + (ng +  0) * DIM_ + d] = __float2bfloat16(s0);
        zh[gbase + (ng +  8) * DIM_ + d] = __float2bfloat16(s1);
        zh[gbase + (ng + 16) * DIM_ + d] = __float2bfloat16(s2);
        zh[gbase + (ng + 24) * DIM_ + d] = __float2bfloat16(s3);
    }
}

// ---------------------------------------------------------------------------
// Fused 2: gather -> u2=relu(agg+z+b2a) -> hb=bn2(u2@w2b+b2b) ->
// f=relu(hb@fc1w+f1b) -> logits -> log_softmax. wC loads over dead hb tile.
// Same interleaved-accumulator dot structure (stride 36 rows).
// ---------------------------------------------------------------------------
__global__ __launch_bounds__(256) void aggmlp2_kernel(const int* __restrict__ offs,
                                                      const int* __restrict__ csr,
                                                      const __hip_bfloat16* __restrict__ zh,
                                                      const float* __restrict__ b2a,
                                                      const float* __restrict__ w2b,
                                                      const float* __restrict__ b2b,
                                                      const float* __restrict__ g2,
                                                      const float* __restrict__ be2,
                                                      const float* __restrict__ m2,
                                                      const float* __restrict__ v2,
                                                      const float* __restrict__ f1w,
                                                      const float* __restrict__ f1b,
                                                      const float* __restrict__ f2w,
                                                      const float* __restrict__ f2b,
                                                      float* __restrict__ out) {
    __shared__ __align__(16) float A[32 * 36];
    __shared__ __align__(16) float BC[DIM_ * NC_];   // hb tile (32x36=1152) then wC (1280)
    __shared__ float wA[DIM_ * DIM_];
    __shared__ float wB[DIM_ * DIM_];
    int tid = threadIdx.x;
    for (int i = tid; i < DIM_ * DIM_; i += 256) { wA[i] = w2b[i]; wB[i] = f1w[i]; }

    int nl = tid >> 3, lane = tid & 7;
    int node = blockIdx.x * 32 + nl;
    int beg = offs[node], end = offs[node + 1];
    float a0 = 0.f, a1 = 0.f, a2 = 0.f, a3 = 0.f;
    gather_row(csr, (const char*)zh, beg, end, lane << 3, a0, a1, a2, a3);
    {
        float* p = &A[nl * 36 + lane * 4];
        p[0] = a0; p[1] = a1; p[2] = a2; p[3] = a3;
    }
    __syncthreads();

    int d = tid & 31, ng = tid >> 5;
    size_t gbase = (size_t)blockIdx.x * 32 * DIM_;

    // u2 = relu(agg + z + b2a)
    {
        float bv = b2a[d];
#pragma unroll
        for (int r = 0; r < 4; ++r) {
            int n = r * 8 + ng;
            float zv = __bfloat162float(zh[gbase + n * DIM_ + d]);
            A[n * 36 + d] = fmaxf(A[n * 36 + d] + zv + bv, 0.f);
        }
    }
    __syncthreads();

    float sc2 = g2[d] * rsqrtf(v2[d] + 1e-5f);
    float sh2 = be2[d] - m2[d] * sc2;

    // hb = bn2(u2 @ w2b + b2b)   (no relu between conv2 and bn2)
    {
        float s0 = b2b[d], s1 = s0, s2 = s0, s3 = s0;
        const float4* r0 = (const float4*)&A[(ng +  0) * 36];
        const float4* r1 = (const float4*)&A[(ng +  8) * 36];
        const float4* r2 = (const float4*)&A[(ng + 16) * 36];
        const float4* r3 = (const float4*)&A[(ng + 24) * 36];
#pragma unroll
        for (int kc = 0; kc < 8; ++kc) {
            float w0 = wA[(kc * 4 + 0) * DIM_ + d];
            float w1 = wA[(kc * 4 + 1) * DIM_ + d];
            float w2 = wA[(kc * 4 + 2) * DIM_ + d];
            float w3 = wA[(kc * 4 + 3) * DIM_ + d];
            float4 a;
            a = r0[kc]; s0 += a.x * w0 + a.y * w1 + a.z * w2 + a.w * w3;
            a = r1[kc]; s1 += a.x * w0 + a.y * w1 + a.z * w2 + a.w * w3;
            a = r2[kc]; s2 += a.x * w0 + a.y * w1 + a.z * w2 + a.w * w3;
            a = r3[kc]; s3 += a.x * w0 + a.y * w1 + a.z * w2 + a.w * w3;
        }
        BC[(ng +  0) * 36 + d] = s0 * sc2 + sh2;
        BC[(ng +  8) * 36 + d] = s1 * sc2 + sh2;
        BC[(ng + 16) * 36 + d] = s2 * sc2 + sh2;
        BC[(ng + 24) * 36 + d] = s3 * sc2 + sh2;
    }
    __syncthreads();

    // f = relu(hb @ fc1w + fc1b) -> overwrite A (u2 dead)
    {
        float s0 = f1b[d], s1 = s0, s2 = s0, s3 = s0;
        const float4* r0 = (const float4*)&BC[(ng +  0) * 36];
        const float4* r1 = (const float4*)&BC[(ng +  8) * 36];
        const float4* r2 = (const float4*)&BC[(ng + 16) * 36];
        const float4* r3 = (const float4*)&BC[(ng + 24) * 36];
#pragma unroll
        for (int kc = 0; kc < 8; ++kc) {
            float w0 = wB[(kc * 4 + 0) * DIM_ + d];
            float w1 = wB[(kc * 4 + 1) * DIM_ + d];
            float w2 = wB[(kc * 4 + 2) * DIM_ + d];
            float w3 = wB[(kc * 4 + 3) * DIM_ + d];
            float4 a;
            a = r0[kc]; s0 += a.x * w0 + a.y * w1 + a.z * w2 + a.w * w3;
            a = r1[kc]; s1 += a.x * w0 + a.y * w1 + a.z * w2 + a.w * w3;
            a = r2[kc]; s2 += a.x * w0 + a.y * w1 + a.z * w2 + a.w * w3;
            a = r3[kc]; s3 += a.x * w0 + a.y * w1 + a.z * w2 + a.w * w3;
        }
        A[(ng +  0) * 36 + d] = fmaxf(s0, 0.f);
        A[(ng +  8) * 36 + d] = fmaxf(s1, 0.f);
        A[(ng + 16) * 36 + d] = fmaxf(s2, 0.f);
        A[(ng + 24) * 36 + d] = fmaxf(s3, 0.f);
    }
    __syncthreads();
    // hb dead -> load wC over BC
    for (int i = tid; i < DIM_ * NC_; i += 256) BC[i] = f2w[i];
    __syncthreads();

    // logits + log_softmax (thread d owns col d and col 32+(d&7))
    int c2 = 32 + (d & 7);
    float l00 = f2b[d], l01 = l00, l02 = l00, l03 = l00;
    float cb = f2b[c2];
    float l10 = cb, l11 = cb, l12 = cb, l13 = cb;
    {
        const float4* r0 = (const float4*)&A[(ng +  0) * 36];
        const float4* r1 = (const float4*)&A[(ng +  8) * 36];
        const float4* r2 = (const float4*)&A[(ng + 16) * 36];
        const float4* r3 = (const float4*)&A[(ng + 24) * 36];
#pragma unroll
        for (int kc = 0; kc < 8; ++kc) {
            float wa0 = BC[(kc * 4 + 0) * NC_ + d];
            float wa1 = BC[(kc * 4 + 1) * NC_ + d];
            float wa2 = BC[(kc * 4 + 2) * NC_ + d];
            float wa3 = BC[(kc * 4 + 3) * NC_ + d];
            float wb0 = BC[(kc * 4 + 0) * NC_ + c2];
            float wb1 = BC[(kc * 4 + 1) * NC_ + c2];
            float wb2 = BC[(kc * 4 + 2) * NC_ + c2];
            float wb3 = BC[(kc * 4 + 3) * NC_ + c2];
            float4 a;
            a = r0[kc];
            l00 += a.x * wa0 + a.y * wa1 + a.z * wa2 + a.w * wa3;
            l10 += a.x * wb0 + a.y * wb1 + a.z * wb2 + a.w * wb3;
            a = r1[kc];
            l01 += a.x * wa0 + a.y * wa1 + a.z * wa2 + a.w * wa3;
            l11 += a.x * wb0 + a.y * wb1 + a.z * wb2 + a.w * wb3;
            a = r2[kc];
            l02 += a.x * wa0 + a.y * wa1 + a.z * wa2 + a.w * wa3;
            l12 += a.x * wb0 + a.y * wb1 + a.z * wb2 + a.w * wb3;
            a = r3[kc];
            l03 += a.x * wa0 + a.y * wa1 + a.z * wa2 + a.w * wa3;
            l13 += a.x * wb0 + a.y * wb1 + a.z * wb2 + a.w * wb3;
        }
    }
#pragma unroll
    for (int r = 0; r < 4; ++r) {
        float l0 = (r == 0) ? l00 : (r == 1) ? l01 : (r == 2) ? l02 : l03;
        float l1 = (r == 0) ? l10 : (r == 1) ? l11 : (r == 2) ? l12 : l13;
        int n = r * 8 + ng;
        float mx = fmaxf(l0, l1);
#pragma unroll
        for (int off = 16; off; off >>= 1) mx = fmaxf(mx, __shfl_xor(mx, off));
        float se = __expf(l0 - mx) + ((d < 8) ? __expf(l1 - mx) : 0.f);
#pragma unroll
        for (int off = 16; off; off >>= 1) se += __shfl_xor(se, off);
        float lse = mx + __logf(se);
        size_t ob = (size_t)(blockIdx.x * 32 + n) * NC_;
        out[ob + d] = l0 - lse;
        if (d < 8) out[ob + 32 + d] = l1 - lse;
    }
}

// ---------------------------------------------------------------------------
extern "C" void kernel_launch(void* const* d_in, const int* in_sizes, int n_in,
                              void* d_out, int out_size, void* d_ws, size_t ws_size,
                              hipStream_t stream) {
    const float* x   = (const float*)d_in[0];
    const void*  edg = d_in[1];
    const float* w1a = (const float*)d_in[2];
    const float* b1a = (const float*)d_in[3];
    const float* w1b = (const float*)d_in[4];
    const float* b1b = (const float*)d_in[5];
    const float* w2a = (const float*)d_in[6];
    const float* b2a = (const float*)d_in[7];
    const float* w2b = (const float*)d_in[8];
    const float* b2b = (const float*)d_in[9];
    const float* g1  = (const float*)d_in[10];
    const float* be1 = (const float*)d_in[11];
    const float* m1  = (const float*)d_in[12];
    const float* v1  = (const float*)d_in[13];
    const float* g2  = (const float*)d_in[14];
    const float* be2 = (const float*)d_in[15];
    const float* m2  = (const float*)d_in[16];
    const float* v2  = (const float*)d_in[17];
    const float* f1w = (const float*)d_in[18];
    const float* f1b = (const float*)d_in[19];
    const float* f2w = (const float*)d_in[20];
    const float* f2b = (const float*)d_in[21];
    float* out = (float*)d_out;

    // Workspace layout (byte offsets, 128B-aligned)
    char* ws = (char*)d_ws;
    int* done   = (int*)ws;                      // 4 B (memset each launch)
    int* bcnt   = (int*)(ws + 256);              // 782 ints (pad 3328)
    int* bbase  = (int*)(ws + 3584);             // 782 ints (pad 3328)
    int* ghist  = (int*)(ws + 6912);             // 256*782 ints
    int* gcur   = (int*)(ws + 807680);           // 256*782 ints (chunk-major)
    int* offs   = (int*)(ws + 1608448);          // N+1 ints (pad 400128)
    int* packed = (int*)(ws + 2008576);          // E ints
    int* csr    = (int*)(ws + 8408576);          // E ints
    __hip_bfloat16* yh = (__hip_bfloat16*)(ws + 14808576);  // N*DIM bf16
    __hip_bfloat16* zh = (__hip_bfloat16*)(ws + 21208576);  // N*DIM bf16

    hipMemsetAsync(done, 0, 4, stream);

    // ---- Build per-node CSR (deterministic, no global atomics) ----
    chist_kernel<<<NCHUNK, 256, 0, stream>>>(edg, ghist);
    colscan_kernel<<<CS_NB, 256, 0, stream>>>(ghist, gcur, bcnt, bbase, offs, done);
    dscatter_kernel<<<NCHUNK, 256, 0, stream>>>(edg, bbase, gcur, packed);
    fat_kernel<<<NB_BKT + PROJ_NB, 256, 0, stream>>>(bcnt, bbase, packed, offs, csr,
                                                     x, w1a, yh);

    // ---- Layer 1 (proj folded pre-aggregation) ----
    aggmlp1_kernel<<<N_ / 32, 256, 0, stream>>>(offs, csr, yh, b1a, w1b, b1b,
                                                g1, be1, m1, v1, w2a, zh);

    // ---- Layer 2 + head (w2a folded pre-aggregation) ----
    aggmlp2_kernel<<<N_ / 32, 256, 0, stream>>>(offs, csr, zh, b2a, w2b, b2b,
                                                g2, be2, m2, v2, f1w, f1b,
                                                f2w, f2b, out);
}

// Round 3
// 303.698 us; speedup vs baseline: 2.7639x; 1.0293x over previous
//
#include <hip/hip_runtime.h>
#include <hip/hip_bf16.h>

// Problem constants
static constexpr int N_   = 100000;
static constexpr int E_   = 1600000;
static constexpr int FIN_ = 128;
static constexpr int DIM_ = 32;
static constexpr int NC_  = 40;
static constexpr int NB_BKT = (N_ + 127) / 128;   // 782 buckets of 128 dst nodes
static constexpr int NCHUNK = 256;                // edge chunks
static constexpr int EPC    = E_ / NCHUNK;        // 6250 edges per chunk (exact)
static constexpr int PROJ_NB = N_ / 32;           // 3125 proj blocks
static constexpr int CS_NB  = (NB_BKT + 7) / 8;   // 98 colscan blocks

__device__ __forceinline__ int edge_at(const void* e, int is64, long long i) {
    return is64 ? (int)((const long long*)e)[i] : ((const int*)e)[i];
}

__device__ __forceinline__ float bflo(unsigned u) { return __uint_as_float(u << 16); }
__device__ __forceinline__ float bfhi(unsigned u) { return __uint_as_float(u & 0xffff0000u); }

// Per-block edge dtype detection (reference says int64; JAX x64-off gives int32;
// int32 read as int64 -> garbage high words -> out of [0,N) w.h.p.)
#define DETECT_FLAG(edge, sflag)                                        \
    if (threadIdx.x < 64) {                                             \
        const long long* p_ = (const long long*)(edge);                 \
        long long v_ = p_[threadIdx.x];                                 \
        bool bad_ = (v_ < 0 || v_ >= (long long)N_);                    \
        unsigned long long m_ = __ballot(bad_);                         \
        if (threadIdx.x == 0) sflag = (m_ == 0ull) ? 1 : 0;             \
    }                                                                   \
    __syncthreads();

// ---------------------------------------------------------------------------
// Build 1: per-chunk bucket histogram in LDS -> ghist[b][k] (coalesced write)
// ---------------------------------------------------------------------------
__global__ __launch_bounds__(256) void chist_kernel(const void* __restrict__ edge,
                                                    int* __restrict__ ghist) {
    __shared__ int lh[NB_BKT];
    __shared__ int sflag;
    DETECT_FLAG(edge, sflag)
    for (int i = threadIdx.x; i < NB_BKT; i += 256) lh[i] = 0;
    __syncthreads();
    int f = sflag;
    int b = blockIdx.x;
    int end = b * EPC + EPC;
    for (int e = b * EPC + threadIdx.x; e < end; e += 256) {
        int d = edge_at(edge, f, (long long)E_ + e);
        atomicAdd(&lh[d >> 7], 1);           // LDS int atomic
    }
    __syncthreads();
    for (int i = threadIdx.x; i < NB_BKT; i += 256) ghist[b * NB_BKT + i] = lh[i];
}

// ---------------------------------------------------------------------------
// Build 2: column scans, 8 buckets per block via coalesced LDS tile.
// Outputs gcur[b][k] (CHUNK-major -> dscatter reads a coalesced row) and
// bcnt[k]. Last block (ticket) scans bucket totals -> bbase + offs[N].
// ---------------------------------------------------------------------------
__global__ __launch_bounds__(256) void colscan_kernel(const int* __restrict__ ghist,
                                                      int* __restrict__ gcur,
                                                      int* __restrict__ bcnt,
                                                      int* __restrict__ bbase,
                                                      int* __restrict__ offs,
                                                      int* __restrict__ done) {
    __shared__ int tile[256 * 9];   // [chunk b][bucket kk], padded
    __shared__ int a[256];
    __shared__ int lastFlag;
    int tid = threadIdx.x;
    int k0 = blockIdx.x * 8;

    // coalesced-ish load: 8 lanes per chunk-row (32B of one line), 32 rows/pass
    {
        int kk = tid & 7, r0 = tid >> 3;
        for (int p = 0; p < 8; ++p) {
            int b = r0 + p * 32;
            int k = k0 + kk;
            tile[b * 9 + kk] = (k < NB_BKT) ? ghist[b * NB_BKT + k] : 0;
        }
    }
    __syncthreads();

    // scan each of 8 columns over 256 chunks: half-wave (32 lanes) per column,
    // 8 chunks per lane, shuffle-scan of lane sums.
    int c = tid >> 5, lane = tid & 31;
    int v[8]; int s = 0;
#pragma unroll
    for (int r = 0; r < 8; ++r) { v[r] = tile[(lane * 8 + r) * 9 + c]; s += v[r]; }
    int incl = s;
#pragma unroll
    for (int off = 1; off < 32; off <<= 1) {
        int u = __shfl_up(incl, off, 32);
        if (lane >= off) incl += u;
    }
    int ex = incl - s;
    int k = k0 + c;
    if (k < NB_BKT) {
        int run = ex;
#pragma unroll
        for (int r = 0; r < 8; ++r) {
            int b = lane * 8 + r;
            gcur[b * NB_BKT + k] = run;     // exclusive prefix for (chunk b, bucket k)
            run += v[r];
        }
        if (lane == 31) bcnt[k] = run;      // bucket total
    }
    __syncthreads();
    if (tid == 0) {
        __threadfence();                    // release gcur/bcnt before ticket
        int old = atomicAdd(done, 1);
        lastFlag = (old == CS_NB - 1) ? 1 : 0;
    }
    __syncthreads();
    if (lastFlag) {
        __threadfence();                    // acquire other blocks' bcnt
        int b4[4]; int base4 = tid * 4; int t = 0;
#pragma unroll
        for (int j = 0; j < 4; ++j) { int i = base4 + j; b4[j] = (i < NB_BKT) ? bcnt[i] : 0; t += b4[j]; }
        a[tid] = t;
        __syncthreads();
        for (int off = 1; off < 256; off <<= 1) {
            int u = a[tid] + ((tid >= off) ? a[tid - off] : 0);
            __syncthreads(); a[tid] = u; __syncthreads();
        }
        int g = a[tid] - t;
#pragma unroll
        for (int j = 0; j < 4; ++j) { int i = base4 + j; if (i < NB_BKT) bbase[i] = g; g += b4[j]; }
        if (tid == 255) offs[N_] = a[255];  // == E_
    }
}

// ---------------------------------------------------------------------------
// Build 3: deterministic scatter into bucket regions; cursors in LDS.
// ---------------------------------------------------------------------------
__global__ __launch_bounds__(256) void dscatter_kernel(const void* __restrict__ edge,
                                                       const int* __restrict__ bbase,
                                                       const int* __restrict__ gcur,
                                                       int* __restrict__ packed) {
    __shared__ int cur[NB_BKT];
    __shared__ int sflag;
    DETECT_FLAG(edge, sflag)
    int b = blockIdx.x, tid = threadIdx.x;
    for (int k = tid; k < NB_BKT; k += 256) cur[k] = bbase[k] + gcur[b * NB_BKT + k];
    __syncthreads();
    int f = sflag;
    int end = b * EPC + EPC;
    for (int e = b * EPC + tid; e < end; e += 256) {
        int s = edge_at(edge, f, e);
        int d = edge_at(edge, f, (long long)E_ + e);
        int pos = atomicAdd(&cur[d >> 7], 1);     // LDS int atomic
        packed[pos] = s | ((d & 127) << 17);      // N < 2^17
    }
}

// ---------------------------------------------------------------------------
// Build 4 ∥ proj: blocks [0,782): per-bucket counting sort -> offs[] + csr[];
// blocks [782, 782+3125): yh = bf16(x @ w1a) (interleaved-acc dense dot).
// ---------------------------------------------------------------------------
__global__ __launch_bounds__(256) void fat_kernel(const int* __restrict__ bcnt,
                                                  const int* __restrict__ bbase,
                                                  const int* __restrict__ packed,
                                                  int* __restrict__ offs,
                                                  int* __restrict__ csr,
                                                  const float* __restrict__ x,
                                                  const float* __restrict__ w,
                                                  __hip_bfloat16* __restrict__ yh) {
    __shared__ __align__(16) char smem[32768];
    int tid = threadIdx.x;
    if (blockIdx.x < NB_BKT) {
        // ---- bsort ----
        int* c   = (int*)smem;
        int* cur = (int*)smem + 128;
        int b = blockIdx.x;
        int beg = bbase[b], cnt = bcnt[b];
        if (tid < 128) c[tid] = 0;
        __syncthreads();
        for (int i = tid; i < cnt; i += 256)
            atomicAdd(&c[packed[beg + i] >> 17], 1);
        __syncthreads();
        int myv = (tid < 128) ? c[tid] : 0;
        for (int off = 1; off < 128; off <<= 1) {
            int t = 0;
            if (tid < 128) t = c[tid] + ((tid >= off) ? c[tid - off] : 0);
            __syncthreads();
            if (tid < 128) c[tid] = t;
            __syncthreads();
        }
        if (tid < 128) {
            int ex = c[tid] - myv;
            cur[tid] = ex;
            int node = b * 128 + tid;
            if (node < N_) offs[node] = beg + ex;
        }
        __syncthreads();
        for (int i = tid; i < cnt; i += 256) {
            int v = packed[beg + i];
            int p = atomicAdd(&cur[v >> 17], 1);
            csr[beg + p] = v & 0x1FFFF;
        }
    } else {
        // ---- proj1: 32 nodes per block, interleaved accumulators ----
        float* wsm = (float*)smem;               // 16 KB
        float* xs  = (float*)(smem + 16384);     // 16 KB
        const float4* w4 = (const float4*)w;
        float4* ws4 = (float4*)wsm;
        for (int i = tid; i < FIN_ * DIM_ / 4; i += 256) ws4[i] = w4[i];

        int nodeBase = (blockIdx.x - NB_BKT) * 32;
        const float4* x4 = (const float4*)(x + (size_t)nodeBase * FIN_);
        float4* xs4 = (float4*)xs;
        for (int i = tid; i < 32 * FIN_ / 4; i += 256) xs4[i] = x4[i];
        __syncthreads();

        int d = tid & 31, ns = tid >> 5;
        float acc0 = 0.f, acc1 = 0.f, acc2 = 0.f, acc3 = 0.f;
        const float4* r0 = (const float4*)&xs[(ns +  0) * FIN_];
        const float4* r1 = (const float4*)&xs[(ns +  8) * FIN_];
        const float4* r2 = (const float4*)&xs[(ns + 16) * FIN_];
        const float4* r3 = (const float4*)&xs[(ns + 24) * FIN_];
#pragma unroll
        for (int kc = 0; kc < FIN_ / 4; ++kc) {
            float w0 = wsm[(kc * 4 + 0) * DIM_ + d];
            float w1 = wsm[(kc * 4 + 1) * DIM_ + d];
            float w2 = wsm[(kc * 4 + 2) * DIM_ + d];
            float w3 = wsm[(kc * 4 + 3) * DIM_ + d];
            float4 a;
            a = r0[kc]; acc0 += a.x * w0 + a.y * w1 + a.z * w2 + a.w * w3;
            a = r1[kc]; acc1 += a.x * w0 + a.y * w1 + a.z * w2 + a.w * w3;
            a = r2[kc]; acc2 += a.x * w0 + a.y * w1 + a.z * w2 + a.w * w3;
            a = r3[kc]; acc3 += a.x * w0 + a.y * w1 + a.z * w2 + a.w * w3;
        }
        __hip_bfloat16* yo = yh + (size_t)nodeBase * DIM_ + d;
        yo[(ns +  0) * DIM_] = __float2bfloat16(acc0);
        yo[(ns +  8) * DIM_] = __float2bfloat16(acc1);
        yo[(ns + 16) * DIM_] = __float2bfloat16(acc2);
        yo[(ns + 24) * DIM_] = __float2bfloat16(acc3);
    }
}

// ---------------------------------------------------------------------------
// Gather: 8 lanes x 8B (uint2) per 64B row, 4-wide unroll.
// Node-parallel, per-lane private accumulators — NO atomics.
// ---------------------------------------------------------------------------
__device__ __forceinline__ void gather_row(const int* __restrict__ csr,
                                           const char* __restrict__ vb,
                                           int beg, int end, int loff,
                                           float& a0, float& a1, float& a2, float& a3) {
    int i = beg;
    for (; i + 3 < end; i += 4) {
        int s0 = csr[i], s1 = csr[i + 1], s2 = csr[i + 2], s3 = csr[i + 3];
        uint2 u0 = *(const uint2*)(vb + (((size_t)s0) << 6) + loff);
        uint2 u1 = *(const uint2*)(vb + (((size_t)s1) << 6) + loff);
        uint2 u2 = *(const uint2*)(vb + (((size_t)s2) << 6) + loff);
        uint2 u3 = *(const uint2*)(vb + (((size_t)s3) << 6) + loff);
        a0 += (bflo(u0.x) + bflo(u1.x)) + (bflo(u2.x) + bflo(u3.x));
        a1 += (bfhi(u0.x) + bfhi(u1.x)) + (bfhi(u2.x) + bfhi(u3.x));
        a2 += (bflo(u0.y) + bflo(u1.y)) + (bflo(u2.y) + bflo(u3.y));
        a3 += (bfhi(u0.y) + bfhi(u1.y)) + (bfhi(u2.y) + bfhi(u3.y));
    }
    for (; i < end; ++i) {
        int s0 = csr[i];
        uint2 u0 = *(const uint2*)(vb + (((size_t)s0) << 6) + loff);
        a0 += bflo(u0.x); a1 += bfhi(u0.x); a2 += bflo(u0.y); a3 += bfhi(u0.y);
    }
}

// ---------------------------------------------------------------------------
// Gather + u: u[node][d] = relu(agg[node][d] + self[node][d] + bias[d]).
// Zero LDS, low VGPR -> max wave occupancy to hide scattered-load latency.
// 32 nodes/block, 8 lanes/node, fully coalesced float4 output.
// ---------------------------------------------------------------------------
__global__ __launch_bounds__(256) void gathu_kernel(const int* __restrict__ offs,
                                                    const int* __restrict__ csr,
                                                    const __hip_bfloat16* __restrict__ vh,
                                                    const float* __restrict__ bias,
                                                    float* __restrict__ u) {
    int tid = threadIdx.x;
    int nl = tid >> 3, slot = tid & 7;
    int node = blockIdx.x * 32 + nl;
    int beg = offs[node], end = offs[node + 1];
    float a0 = 0.f, a1 = 0.f, a2 = 0.f, a3 = 0.f;
    gather_row(csr, (const char*)vh, beg, end, slot << 3, a0, a1, a2, a3);
    uint2 uy = *(const uint2*)((const char*)vh + (((size_t)node) << 6) + (slot << 3));
    float4 bv = ((const float4*)bias)[slot];
    float4 r;
    r.x = fmaxf(a0 + bflo(uy.x) + bv.x, 0.f);
    r.y = fmaxf(a1 + bfhi(uy.x) + bv.y, 0.f);
    r.z = fmaxf(a2 + bflo(uy.y) + bv.z, 0.f);
    r.w = fmaxf(a3 + bfhi(uy.y) + bv.w, 0.f);
    ((float4*)u)[(size_t)blockIdx.x * 256 + tid] = r;
}

// ---------------------------------------------------------------------------
// Dense MLP 1: u -> hb=bn1(relu(u@w1b+b1b)) -> zh=bf16(hb@w2a).
// Pure LDS/VALU; interleaved accumulators (high VGPR is fine here).
// ---------------------------------------------------------------------------
__global__ __launch_bounds__(256) void mlp1_kernel(const float* __restrict__ u,
                                                   const float* __restrict__ w1b,
                                                   const float* __restrict__ b1b,
                                                   const float* __restrict__ g1,
                                                   const float* __restrict__ be1,
                                                   const float* __restrict__ m1,
                                                   const float* __restrict__ v1,
                                                   const float* __restrict__ w2a,
                                                   __hip_bfloat16* __restrict__ zh) {
    __shared__ __align__(16) float A[32 * 36];
    __shared__ __align__(16) float B[32 * 36];
    __shared__ float w1s[DIM_ * DIM_];
    __shared__ float w2s[DIM_ * DIM_];
    int tid = threadIdx.x;
    for (int i = tid; i < DIM_ * DIM_; i += 256) { w1s[i] = w1b[i]; w2s[i] = w2a[i]; }
    {
        int n = tid >> 3, sl = tid & 7;
        *(float4*)&A[n * 36 + sl * 4] = ((const float4*)u)[(size_t)blockIdx.x * 256 + tid];
    }
    __syncthreads();

    int d = tid & 31, ng = tid >> 5;
    size_t gbase = (size_t)blockIdx.x * 32 * DIM_;

    float sc1 = g1[d] * rsqrtf(v1[d] + 1e-5f);
    float sh1 = be1[d] - m1[d] * sc1;

    // hb = bn1(relu(u @ w1b + b1b))
    {
        float s0 = b1b[d], s1 = s0, s2 = s0, s3 = s0;
        const float4* r0 = (const float4*)&A[(ng +  0) * 36];
        const float4* r1 = (const float4*)&A[(ng +  8) * 36];
        const float4* r2 = (const float4*)&A[(ng + 16) * 36];
        const float4* r3 = (const float4*)&A[(ng + 24) * 36];
#pragma unroll
        for (int kc = 0; kc < 8; ++kc) {
            float w0 = w1s[(kc * 4 + 0) * DIM_ + d];
            float w1 = w1s[(kc * 4 + 1) * DIM_ + d];
            float w2 = w1s[(kc * 4 + 2) * DIM_ + d];
            float w3 = w1s[(kc * 4 + 3) * DIM_ + d];
            float4 a;
            a = r0[kc]; s0 += a.x * w0 + a.y * w1 + a.z * w2 + a.w * w3;
            a = r1[kc]; s1 += a.x * w0 + a.y * w1 + a.z * w2 + a.w * w3;
            a = r2[kc]; s2 += a.x * w0 + a.y * w1 + a.z * w2 + a.w * w3;
            a = r3[kc]; s3 += a.x * w0 + a.y * w1 + a.z * w2 + a.w * w3;
        }
        B[(ng +  0) * 36 + d] = fmaxf(s0, 0.f) * sc1 + sh1;
        B[(ng +  8) * 36 + d] = fmaxf(s1, 0.f) * sc1 + sh1;
        B[(ng + 16) * 36 + d] = fmaxf(s2, 0.f) * sc1 + sh1;
        B[(ng + 24) * 36 + d] = fmaxf(s3, 0.f) * sc1 + sh1;
    }
    __syncthreads();

    // z = hb @ w2a -> bf16
    {
        float s0 = 0.f, s1 = 0.f, s2 = 0.f, s3 = 0.f;
        const float4* r0 = (const float4*)&B[(ng +  0) * 36];
        const float4* r1 = (const float4*)&B[(ng +  8) * 36];
        const float4* r2 = (const float4*)&B[(ng + 16) * 36];
        const float4* r3 = (const float4*)&B[(ng + 24) * 36];
#pragma unroll
        for (int kc = 0; kc < 8; ++kc) {
            float w0 = w2s[(kc * 4 + 0) * DIM_ + d];
            float w1 = w2s[(kc * 4 + 1) * DIM_ + d];
            float w2 = w2s[(kc * 4 + 2) * DIM_ + d];
            float w3 = w2s[(kc * 4 + 3) * DIM_ + d];
            float4 a;
            a = r0[kc]; s0 += a.x * w0 + a.y * w1 + a.z * w2 + a.w * w3;
            a = r1[kc]; s1 += a.x * w0 + a.y * w1 + a.z * w2 + a.w * w3;
            a = r2[kc]; s2 += a.x * w0 + a.y * w1 + a.z * w2 + a.w * w3;
            a = r3[kc]; s3 += a.x * w0 + a.y * w1 + a.z * w2 + a.w * w3;
        }
        zh[gbase + (ng +  0) * DIM_ + d] = __float2bfloat16(s0);
        zh[gbase + (ng +  8) * DIM_ + d] = __float2bfloat16(s1);
        zh[gbase + (ng + 16) * DIM_ + d] = __float2bfloat16(s2);
        zh[gbase + (ng + 24) * DIM_ + d] = __float2bfloat16(s3);
    }
}

// ---------------------------------------------------------------------------
// Dense MLP 2 + head: u2 -> hb=bn2(u2@w2b+b2b) -> f=relu(hb@fc1w+f1b)
// -> logits -> log_softmax.
// ---------------------------------------------------------------------------
__global__ __launch_bounds__(256) void mlp2_kernel(const float* __restrict__ u,
                                                   const float* __restrict__ w2b,
                                                   const float* __restrict__ b2b,
                                                   const float* __restrict__ g2,
                                                   const float* __restrict__ be2,
                                                   const float* __restrict__ m2,
                                                   const float* __restrict__ v2,
                                                   const float* __restrict__ f1w,
                                                   const float* __restrict__ f1b,
                                                   const float* __restrict__ f2w,
                                                   const float* __restrict__ f2b,
                                                   float* __restrict__ out) {
    __shared__ __align__(16) float A[32 * 36];
    __shared__ __align__(16) float BC[DIM_ * NC_];   // hb tile (1152) then wC (1280)
    __shared__ float wA[DIM_ * DIM_];
    __shared__ float wB[DIM_ * DIM_];
    int tid = threadIdx.x;
    for (int i = tid; i < DIM_ * DIM_; i += 256) { wA[i] = w2b[i]; wB[i] = f1w[i]; }
    {
        int n = tid >> 3, sl = tid & 7;
        *(float4*)&A[n * 36 + sl * 4] = ((const float4*)u)[(size_t)blockIdx.x * 256 + tid];
    }
    __syncthreads();

    int d = tid & 31, ng = tid >> 5;

    float sc2 = g2[d] * rsqrtf(v2[d] + 1e-5f);
    float sh2 = be2[d] - m2[d] * sc2;

    // hb = bn2(u2 @ w2b + b2b)   (no relu between conv2 and bn2)
    {
        float s0 = b2b[d], s1 = s0, s2 = s0, s3 = s0;
        const float4* r0 = (const float4*)&A[(ng +  0) * 36];
        const float4* r1 = (const float4*)&A[(ng +  8) * 36];
        const float4* r2 = (const float4*)&A[(ng + 16) * 36];
        const float4* r3 = (const float4*)&A[(ng + 24) * 36];
#pragma unroll
        for (int kc = 0; kc < 8; ++kc) {
            float w0 = wA[(kc * 4 + 0) * DIM_ + d];
            float w1 = wA[(kc * 4 + 1) * DIM_ + d];
            float w2 = wA[(kc * 4 + 2) * DIM_ + d];
            float w3 = wA[(kc * 4 + 3) * DIM_ + d];
            float4 a;
            a = r0[kc]; s0 += a.x * w0 + a.y * w1 + a.z * w2 + a.w * w3;
            a = r1[kc]; s1 += a.x * w0 + a.y * w1 + a.z * w2 + a.w * w3;
            a = r2[kc]; s2 += a.x * w0 + a.y * w1 + a.z * w2 + a.w * w3;
            a = r3[kc]; s3 += a.x * w0 + a.y * w1 + a.z * w2 + a.w * w3;
        }
        BC[(ng +  0) * 36 + d] = s0 * sc2 + sh2;
        BC[(ng +  8) * 36 + d] = s1 * sc2 + sh2;
        BC[(ng + 16) * 36 + d] = s2 * sc2 + sh2;
        BC[(ng + 24) * 36 + d] = s3 * sc2 + sh2;
    }
    __syncthreads();

    // f = relu(hb @ fc1w + fc1b) -> overwrite A (u2 dead)
    {
        float s0 = f1b[d], s1 = s0, s2 = s0, s3 = s0;
        const float4* r0 = (const float4*)&BC[(ng +  0) * 36];
        const float4* r1 = (const float4*)&BC[(ng +  8) * 36];
        const float4* r2 = (const float4*)&BC[(ng + 16) * 36];
        const float4* r3 = (const float4*)&BC[(ng + 24) * 36];
#pragma unroll
        for (int kc = 0; kc < 8; ++kc) {
            float w0 = wB[(kc * 4 + 0) * DIM_ + d];
            float w1 = wB[(kc * 4 + 1) * DIM_ + d];
            float w2 = wB[(kc * 4 + 2) * DIM_ + d];
            float w3 = wB[(kc * 4 + 3) * DIM_ + d];
            float4 a;
            a = r0[kc]; s0 += a.x * w0 + a.y * w1 + a.z * w2 + a.w * w3;
            a = r1[kc]; s1 += a.x * w0 + a.y * w1 + a.z * w2 + a.w * w3;
            a = r2[kc]; s2 += a.x * w0 + a.y * w1 + a.z * w2 + a.w * w3;
            a = r3[kc]; s3 += a.x * w0 + a.y * w1 + a.z * w2 + a.w * w3;
        }
        A[(ng +  0) * 36 + d] = fmaxf(s0, 0.f);
        A[(ng +  8) * 36 + d] = fmaxf(s1, 0.f);
        A[(ng + 16) * 36 + d] = fmaxf(s2, 0.f);
        A[(ng + 24) * 36 + d] = fmaxf(s3, 0.f);
    }
    __syncthreads();
    // hb dead -> load wC over BC
    for (int i = tid; i < DIM_ * NC_; i += 256) BC[i] = f2w[i];
    __syncthreads();

    // logits + log_softmax (thread d owns col d and col 32+(d&7))
    int c2 = 32 + (d & 7);
    float l00 = f2b[d], l01 = l00, l02 = l00, l03 = l00;
    float cb = f2b[c2];
    float l10 = cb, l11 = cb, l12 = cb, l13 = cb;
    {
        const float4* r0 = (const float4*)&A[(ng +  0) * 36];
        const float4* r1 = (const float4*)&A[(ng +  8) * 36];
        const float4* r2 = (const float4*)&A[(ng + 16) * 36];
        const float4* r3 = (const float4*)&A[(ng + 24) * 36];
#pragma unroll
        for (int kc = 0; kc < 8; ++kc) {
            float wa0 = BC[(kc * 4 + 0) * NC_ + d];
            float wa1 = BC[(kc * 4 + 1) * NC_ + d];
            float wa2 = BC[(kc * 4 + 2) * NC_ + d];
            float wa3 = BC[(kc * 4 + 3) * NC_ + d];
            float wb0 = BC[(kc * 4 + 0) * NC_ + c2];
            float wb1 = BC[(kc * 4 + 1) * NC_ + c2];
            float wb2 = BC[(kc * 4 + 2) * NC_ + c2];
            float wb3 = BC[(kc * 4 + 3) * NC_ + c2];
            float4 a;
            a = r0[kc];
            l00 += a.x * wa0 + a.y * wa1 + a.z * wa2 + a.w * wa3;
            l10 += a.x * wb0 + a.y * wb1 + a.z * wb2 + a.w * wb3;
            a = r1[kc];
            l01 += a.x * wa0 + a.y * wa1 + a.z * wa2 + a.w * wa3;
            l11 += a.x * wb0 + a.y * wb1 + a.z * wb2 + a.w * wb3;
            a = r2[kc];
            l02 += a.x * wa0 + a.y * wa1 + a.z * wa2 + a.w * wa3;
            l12 += a.x * wb0 + a.y * wb1 + a.z * wb2 + a.w * wb3;
            a = r3[kc];
            l03 += a.x * wa0 + a.y * wa1 + a.z * wa2 + a.w * wa3;
            l13 += a.x * wb0 + a.y * wb1 + a.z * wb2 + a.w * wb3;
        }
    }
#pragma unroll
    for (int r = 0; r < 4; ++r) {
        float l0 = (r == 0) ? l00 : (r == 1) ? l01 : (r == 2) ? l02 : l03;
        float l1 = (r == 0) ? l10 : (r == 1) ? l11 : (r == 2) ? l12 : l13;
        int n = r * 8 + ng;
        float mx = fmaxf(l0, l1);
#pragma unroll
        for (int off = 16; off; off >>= 1) mx = fmaxf(mx, __shfl_xor(mx, off));
        float se = __expf(l0 - mx) + ((d < 8) ? __expf(l1 - mx) : 0.f);
#pragma unroll
        for (int off = 16; off; off >>= 1) se += __shfl_xor(se, off);
        float lse = mx + __logf(se);
        size_t ob = (size_t)(blockIdx.x * 32 + n) * NC_;
        out[ob + d] = l0 - lse;
        if (d < 8) out[ob + 32 + d] = l1 - lse;
    }
}

// ---------------------------------------------------------------------------
extern "C" void kernel_launch(void* const* d_in, const int* in_sizes, int n_in,
                              void* d_out, int out_size, void* d_ws, size_t ws_size,
                              hipStream_t stream) {
    const float* x   = (const float*)d_in[0];
    const void*  edg = d_in[1];
    const float* w1a = (const float*)d_in[2];
    const float* b1a = (const float*)d_in[3];
    const float* w1b = (const float*)d_in[4];
    const float* b1b = (const float*)d_in[5];
    const float* w2a = (const float*)d_in[6];
    const float* b2a = (const float*)d_in[7];
    const float* w2b = (const float*)d_in[8];
    const float* b2b = (const float*)d_in[9];
    const float* g1  = (const float*)d_in[10];
    const float* be1 = (const float*)d_in[11];
    const float* m1  = (const float*)d_in[12];
    const float* v1  = (const float*)d_in[13];
    const float* g2  = (const float*)d_in[14];
    const float* be2 = (const float*)d_in[15];
    const float* m2  = (const float*)d_in[16];
    const float* v2  = (const float*)d_in[17];
    const float* f1w = (const float*)d_in[18];
    const float* f1b = (const float*)d_in[19];
    const float* f2w = (const float*)d_in[20];
    const float* f2b = (const float*)d_in[21];
    float* out = (float*)d_out;

    // Workspace layout (byte offsets, 128B-aligned)
    char* ws = (char*)d_ws;
    int* done   = (int*)ws;                      // 4 B (memset each launch)
    int* bcnt   = (int*)(ws + 256);              // 782 ints (pad 3328)
    int* bbase  = (int*)(ws + 3584);             // 782 ints (pad 3328)
    int* ghist  = (int*)(ws + 6912);             // 256*782 ints
    int* gcur   = (int*)(ws + 807680);           // 256*782 ints (chunk-major)
    int* offs   = (int*)(ws + 1608448);          // N+1 ints (pad 400128)
    int* packed = (int*)(ws + 2008576);          // E ints
    int* csr    = (int*)(ws + 8408576);          // E ints
    __hip_bfloat16* yh = (__hip_bfloat16*)(ws + 14808576);  // N*DIM bf16
    __hip_bfloat16* zh = (__hip_bfloat16*)(ws + 21208576);  // N*DIM bf16
    float* u    = (float*)(ws + 27608576);       // N*DIM f32 (reused both layers)

    hipMemsetAsync(done, 0, 4, stream);

    // ---- Build per-node CSR (deterministic, no global atomics) ----
    chist_kernel<<<NCHUNK, 256, 0, stream>>>(edg, ghist);
    colscan_kernel<<<CS_NB, 256, 0, stream>>>(ghist, gcur, bcnt, bbase, offs, done);
    dscatter_kernel<<<NCHUNK, 256, 0, stream>>>(edg, bbase, gcur, packed);
    fat_kernel<<<NB_BKT + PROJ_NB, 256, 0, stream>>>(bcnt, bbase, packed, offs, csr,
                                                     x, w1a, yh);

    // ---- Layer 1: gather+u (latency-tuned) then dense MLP (compute-tuned) ----
    gathu_kernel<<<N_ / 32, 256, 0, stream>>>(offs, csr, yh, b1a, u);
    mlp1_kernel<<<N_ / 32, 256, 0, stream>>>(u, w1b, b1b, g1, be1, m1, v1, w2a, zh);

    // ---- Layer 2 + head ----
    gathu_kernel<<<N_ / 32, 256, 0, stream>>>(offs, csr, zh, b2a, u);
    mlp2_kernel<<<N_ / 32, 256, 0, stream>>>(u, w2b, b2b, g2, be2, m2, v2,
                                             f1w, f1b, f2w, f2b, out);
}